// Round 8
// baseline (172.321 us; speedup 1.0000x reference)
//
#include <hip/hip_runtime.h>

#define CIN 64
#define COUT 96
#define HW_  1024
#define PPB 16
#define NTHR 512
#define NITER 5
#define NMF_EPS 1e-20f

__global__ __launch_bounds__(NTHR) void nmf_kernel(
    const float* __restrict__ x,
    const float* __restrict__ w,
    const float* __restrict__ h0,
    float* __restrict__ out)
{
    __shared__ float  Hs[PPB][COUT + 4];  // [p][j], row = 100 floats (400B, 16B-aligned)
    __shared__ float  Tsp[CIN][20];       // [i][p], row = 20 floats (80B, 16B-aligned)
    __shared__ float4 Par[8];             // per-wave partial sums (4 px each)

    const int t = threadIdx.x;
    const int tile = blockIdx.x;
    const int b = tile >> 6;              // 4 batches * 64 tiles
    const int hw0 = (tile & 63) << 4;     // 16 pixels per tile

    // stage-1 identity: thread = (i-row, pixel-pair); wave-uniform ppair -> Hs reads broadcast
    const int i1 = t & 63;
    const int p0 = (t >> 6) << 1;
    // stage-2 identity: thread = (j-lane, pixel-quad); wave-uniform pq -> Tsp reads broadcast
    const int jr = t & 127;               // j, active if < 96
    const int pq = t >> 7;                // 0..3 (4 px each)
    const int wv = t >> 6;                // wave id 0..7; waves (2k,2k+1) pair on pq=k
    const bool act = (jr < COUT);

    // ---- one-time: h init ----
    for (int k = t; k < PPB * COUT; k += NTHR) {
        const int p = k & 15;
        const int j = k >> 4;
        Hs[p][j] = h0[j];
    }

    // ---- one-time: W row i1 -> wreg[96] (stage 1) ----
    float wreg[COUT];
    #pragma unroll
    for (int j = 0; j < COUT; j += 4) {
        const float4 v = *(const float4*)&w[i1 * COUT + j];
        wreg[j] = v.x; wreg[j + 1] = v.y; wreg[j + 2] = v.z; wreg[j + 3] = v.w;
    }
    // ---- one-time: W column jr -> wcol[64] (stage 2) ----
    float wcol[CIN];
    #pragma unroll
    for (int i = 0; i < CIN; ++i) wcol[i] = act ? w[i * COUT + jr] : 0.f;

    // x for this thread's two stage-1 pixels
    const float* xb = x + (size_t)b * CIN * HW_ + hw0;
    const float x0 = xb[(size_t)i1 * HW_ + p0];
    const float x1 = xb[(size_t)i1 * HW_ + p0 + 1];

    __syncthreads();

    #pragma unroll 1
    for (int it = 0; it < NITER; ++it) {
        // ---- stage 1: denom[p][i] = eps + sum_j h[p][j]*W[i][j]; Tsp[i][p] = x/denom ----
        float a0 = 0.f, a1 = 0.f, a2 = 0.f, a3 = 0.f;
        float c0 = 0.f, c1 = 0.f, c2 = 0.f, c3 = 0.f;
        #pragma unroll
        for (int j = 0; j < COUT; j += 4) {
            const float4 hv0 = *(const float4*)&Hs[p0][j];       // broadcast b128
            const float4 hv1 = *(const float4*)&Hs[p0 + 1][j];   // broadcast b128
            a0 += wreg[j] * hv0.x;     a1 += wreg[j + 1] * hv0.y;
            a2 += wreg[j + 2] * hv0.z; a3 += wreg[j + 3] * hv0.w;
            c0 += wreg[j] * hv1.x;     c1 += wreg[j + 1] * hv1.y;
            c2 += wreg[j + 2] * hv1.z; c3 += wreg[j + 3] * hv1.w;
        }
        const float d0 = ((a0 + a1) + (a2 + a3)) + NMF_EPS;
        const float d1 = ((c0 + c1) + (c2 + c3)) + NMF_EPS;
        Tsp[i1][p0]     = x0 / d0;
        Tsp[i1][p0 + 1] = x1 / d1;
        __syncthreads();   // Tsp ready

        // ---- stage 2: u[px] = sum_i W[i][jr] * t[px][i] for px = 4*pq..4*pq+3 ----
        float u0 = 0.f, u1 = 0.f, u2 = 0.f, u3 = 0.f;
        #pragma unroll
        for (int i = 0; i < CIN; ++i) {
            const float4 tv = *(const float4*)&Tsp[i][pq * 4];   // broadcast b128
            u0 += wcol[i] * tv.x; u1 += wcol[i] * tv.y;
            u2 += wcol[i] * tv.z; u3 += wcol[i] * tv.w;
        }
        float hp0 = 0.f, hp1 = 0.f, hp2 = 0.f, hp3 = 0.f;
        if (act) {
            hp0 = Hs[pq * 4 + 0][jr] * (1.f + u0);
            hp1 = Hs[pq * 4 + 1][jr] * (1.f + u1);
            hp2 = Hs[pq * 4 + 2][jr] * (1.f + u2);
            hp3 = Hs[pq * 4 + 3][jr] * (1.f + u3);
        }
        // ---- normalize: per-px sum over all 96 j (64-lane tree + cross-wave pair) ----
        float s0 = hp0, s1 = hp1, s2 = hp2, s3 = hp3;
        #pragma unroll
        for (int d = 32; d >= 1; d >>= 1) {
            s0 += __shfl_xor(s0, d, 64);
            s1 += __shfl_xor(s1, d, 64);
            s2 += __shfl_xor(s2, d, 64);
            s3 += __shfl_xor(s3, d, 64);
        }
        if ((t & 63) == 0) Par[wv] = make_float4(s0, s1, s2, s3);
        __syncthreads();   // Par ready
        const float4 other = Par[wv ^ 1];                        // broadcast
        const float inv0 = 1.f / ((s0 + other.x) + NMF_EPS);
        const float inv1 = 1.f / ((s1 + other.y) + NMF_EPS);
        const float inv2 = 1.f / ((s2 + other.z) + NMF_EPS);
        const float inv3 = 1.f / ((s3 + other.w) + NMF_EPS);
        if (act) {
            Hs[pq * 4 + 0][jr] = hp0 * inv0;
            Hs[pq * 4 + 1][jr] = hp1 * inv1;
            Hs[pq * 4 + 2][jr] = hp2 * inv2;
            Hs[pq * 4 + 3][jr] = hp3 * inv3;
        }
        __syncthreads();   // Hs ready for next iteration
    }

    // ---- write h -> out (B, Cout, H, W) ----
    for (int k = t; k < PPB * COUT; k += NTHR) {
        const int p = k & 15;
        const int j = k >> 4;
        out[(size_t)b * COUT * HW_ + (size_t)j * HW_ + hw0 + p] = Hs[p][j];
    }
}

extern "C" void kernel_launch(void* const* d_in, const int* in_sizes, int n_in,
                              void* d_out, int out_size, void* d_ws, size_t ws_size,
                              hipStream_t stream) {
    const float* x  = (const float*)d_in[0];
    const float* w  = (const float*)d_in[1];
    const float* h0 = (const float*)d_in[2];
    float* out = (float*)d_out;
    nmf_kernel<<<256, NTHR, 0, stream>>>(x, w, h0, out);
}